// Round 1
// 543.010 us; speedup vs baseline: 1.0246x; 1.0246x over previous
//
#include <hip/hip_runtime.h>
#include <math.h>

#define BB 8
#define CC 128
#define HH 256
#define WW 256
#define HWD 65536                      // H*W
#define NOUT (67108864)                // B*C*H*W

// d_out packing (floats): out | attn | w | alpha
#define ATTN_OFF ((size_t)NOUT)
#define W_OFF (ATTN_OFF + (size_t)BB * HWD)      // 67633152
#define ALPHA_OFF (W_OFF + (size_t)BB * CC)      // 67634176

__constant__ float g_declo[16] = {
    -0.00011747678400228192f, 0.0006754494059985568f, -0.0003917403729959771f,
    -0.00487035299301066f,    0.008746094047015655f,  0.013981027917015516f,
    -0.04408825393106472f,    -0.01736930100202211f,  0.128747426620186f,
    0.00047248457399797254f,  -0.2840155429624281f,   -0.015829105256023893f,
    0.5853546836548691f,      0.6756307362980128f,    0.3128715909144659f,
    0.05441584224308161f};

__device__ __forceinline__ float sigmoidf_(float v) {
    return 1.0f / (1.0f + expf(-v));
}

// Closed form of a[t] = sum over (j,k), j in [0,135), k in [0,16), with
// sym(2j+k-14)==t of f[k], f[k] = g_declo[15-k] (reversed dec_lo).
// Derivation: contributions come from idx0 in {t, -1-t, 511-t} that land in
// [-14, 282]. For idx0 = t (always valid, t in [0,255]) the k-range is
// unconstrained -> sum over k with k ≡ t (mod 2). Boundary reflections:
// idx0 = -1-t valid for t<=13 (k <= 13-t, k ≡ 13-t mod 2);
// idx0 = 511-t valid for t>=242 (k >= 257-t, same parity as 257-t).
__device__ __forceinline__ float a_weight(int t) {
    float v = 0.0f;
    for (int k = (t & 1); k < 16; k += 2) v += g_declo[15 - k];
    if (t <= 13) {
        for (int k = 13 - t; k >= 0; k -= 2) v += g_declo[15 - k];
    }
    if (t >= 242) {
        for (int k = 257 - t; k < 16; k += 2) v += g_declo[15 - k];
    }
    return v;
}

// One block per (b,h). 256 threads = 4 waves; wave wv covers channels
// [wv*32, wv*32+32); lane l covers columns 4l..4l+3 (float4).
// Per-channel row dots reduced via per-wave LDS transpose (stride 17,
// conflict-free) instead of a 6-deep shfl chain per channel.
__global__ __launch_bounds__(256) void pass1_kernel(
    const float* __restrict__ x, float* __restrict__ avg_s,
    float* __restrict__ max_s, float* __restrict__ partial) {
    const int blk = blockIdx.x;  // b*256 + h
    const int b = blk >> 8;
    const int h = blk & 255;
    const int tid = threadIdx.x;
    const int wv = tid >> 6;
    const int lane = tid & 63;

    __shared__ __align__(16) float a_sh[256];
    __shared__ float dotc[CC];
    __shared__ __align__(16) float lsum[4][256];
    __shared__ __align__(16) float lmax[4][256];
    __shared__ float T[4][64][17];  // per-wave transpose scratch, stride 17

    a_sh[tid] = a_weight(tid);
    __syncthreads();

    const float4 a4 = reinterpret_cast<const float4*>(a_sh)[lane];
    const float ah = a_sh[h];

    float4 sum4 = {0.f, 0.f, 0.f, 0.f};
    float4 max4 = {-INFINITY, -INFINITY, -INFINITY, -INFINITY};

    const size_t base = (size_t)b * CC * HWD + (size_t)h * WW + (lane << 2);

    for (int g = 0; g < 2; ++g) {
        const int cbase = (wv << 5) + (g << 4);
        float dots[16];
#pragma unroll
        for (int i = 0; i < 16; ++i) {
            const float4 v = *reinterpret_cast<const float4*>(
                x + base + (size_t)(cbase + i) * HWD);
            dots[i] = a4.x * v.x + a4.y * v.y + a4.z * v.z + a4.w * v.w;
            sum4.x += v.x; sum4.y += v.y; sum4.z += v.z; sum4.w += v.w;
            max4.x = fmaxf(max4.x, v.x); max4.y = fmaxf(max4.y, v.y);
            max4.z = fmaxf(max4.z, v.z); max4.w = fmaxf(max4.w, v.w);
        }
        // wave-private LDS transpose: write 16 dots, read one channel's 16
        // lane-partials. Same-wave DS ops complete in order; no barrier
        // needed (buffer is per-wave).
#pragma unroll
        for (int i = 0; i < 16; ++i) T[wv][lane][i] = dots[i];
        const int cr = lane & 15;  // channel within group
        const int q = lane >> 4;   // lane quarter
        float s = 0.f;
#pragma unroll
        for (int j = 0; j < 16; ++j) s += T[wv][(q << 4) + j][cr];
        s += __shfl_xor(s, 16, 64);
        s += __shfl_xor(s, 32, 64);
        if (lane < 16) dotc[cbase + lane] = s;
    }

    reinterpret_cast<float4*>(&lsum[wv][0])[lane] = sum4;
    reinterpret_cast<float4*>(&lmax[wv][0])[lane] = max4;
    __syncthreads();

    // combine 4 waves per column
    const int col = tid;
    const float s = lsum[0][col] + lsum[1][col] + lsum[2][col] + lsum[3][col];
    const float m = fmaxf(fmaxf(lmax[0][col], lmax[1][col]),
                          fmaxf(lmax[2][col], lmax[3][col]));
    const size_t po = (size_t)b * HWD + (size_t)h * WW + col;
    avg_s[po] = s * (1.0f / 128.0f);
    max_s[po] = m;
    if (tid < CC) partial[(size_t)blk * CC + tid] = dotc[tid] * ah;
}

// One block per b, 1024 threads: 8 h-groups x 128 channels reduce the
// partials in parallel, then the squeeze-excite MLP. Writes w and alpha.
__global__ __launch_bounds__(1024) void mlp_kernel(
    const float* __restrict__ partial, const float* __restrict__ fc_w1,
    const float* __restrict__ fc_w2, const float* __restrict__ weight,
    float* __restrict__ w_out, float* __restrict__ alpha_out) {
    const int b = blockIdx.x;
    const int t = threadIdx.x;
    const int c = t & 127;
    const int g = t >> 7;  // 0..7

    float acc = 0.0f;
    for (int h = g; h < HH; h += 8)
        acc += partial[((size_t)(b * HH + h)) * CC + c];

    __shared__ float red[8][CC];
    __shared__ float ysh[CC];
    __shared__ float hsh[8];
    red[g][c] = acc;
    __syncthreads();

    if (t < CC) {
        float y = 0.0f;
#pragma unroll
        for (int i = 0; i < 8; ++i) y += red[i][t];
        ysh[t] = y * (1.0f / (135.0f * 135.0f));
    }
    __syncthreads();
    if (t < 8) {
        float ha = 0.0f;
        for (int k = 0; k < CC; ++k) ha += ysh[k] * fc_w1[t * CC + k];
        hsh[t] = fmaxf(ha, 0.0f);
    }
    __syncthreads();
    if (t < CC) {
        float wa = 0.0f;
#pragma unroll
        for (int i = 0; i < 8; ++i) wa += hsh[i] * fc_w2[t * 8 + i];
        w_out[b * CC + t] = sigmoidf_(wa);
    }
    if (b == 0 && t == 0) alpha_out[0] = sigmoidf_(weight[0]);
}

// Fused: 7x7 conv (zero pad) -> sigmoid -> attn row (LDS + output), then
// stream all 128 channels of row (b,h): out = x*(alpha*attn + (1-alpha)*w).
__global__ __launch_bounds__(256) void conv_mix_kernel(
    const float* __restrict__ x, const float* __restrict__ avg_s,
    const float* __restrict__ max_s, const float* __restrict__ cw,
    const float* __restrict__ wvec, const float* __restrict__ alpha_p,
    float* __restrict__ attn_out, float* __restrict__ out) {
    const int blk = blockIdx.x;  // b*256 + h
    const int b = blk >> 8;
    const int h = blk & 255;
    const int tid = threadIdx.x;
    const int wv = tid >> 6;
    const int lane = tid & 63;

    __shared__ float k0[49], k1[49];
    __shared__ __align__(16) float sA[7][256];
    __shared__ __align__(16) float sM[7][256];
    __shared__ __align__(16) float att[256];
    __shared__ float wrow[CC];

    if (tid < 49) {
        k0[tid] = cw[tid];
        k1[tid] = cw[49 + tid];
    }
    if (tid < CC) wrow[tid] = wvec[b * CC + tid];

#pragma unroll
    for (int r = 0; r < 7; ++r) {
        const int ih = h - 3 + r;
        if (ih >= 0 && ih < HH) {
            sA[r][tid] = avg_s[(size_t)b * HWD + ih * WW + tid];
            sM[r][tid] = max_s[(size_t)b * HWD + ih * WW + tid];
        }
    }
    __syncthreads();

    float acc = 0.0f;
#pragma unroll
    for (int r = 0; r < 7; ++r) {
        const int ih = h - 3 + r;
        if (ih < 0 || ih >= HH) continue;
#pragma unroll
        for (int kw = 0; kw < 7; ++kw) {
            const int iw = tid + kw - 3;
            if (iw < 0 || iw >= WW) continue;
            acc = fmaf(k0[r * 7 + kw], sA[r][iw], acc);
            acc = fmaf(k1[r * 7 + kw], sM[r][iw], acc);
        }
    }
    const float av = sigmoidf_(acc);
    attn_out[(size_t)b * HWD + h * WW + tid] = av;
    att[tid] = av;
    __syncthreads();

    const float alpha = alpha_p[0];
    const float one_m = 1.0f - alpha;
    const float4 at4 = reinterpret_cast<const float4*>(att)[lane];
    const float4 aa4 = {alpha * at4.x, alpha * at4.y, alpha * at4.z,
                        alpha * at4.w};
    const size_t rowbase = (size_t)b * CC * HWD + (size_t)h * WW + (lane << 2);
#pragma unroll 4
    for (int ci = 0; ci < 32; ++ci) {
        const int c = (wv << 5) + ci;
        const float wc = one_m * wrow[c];
        const float4 x4 =
            *reinterpret_cast<const float4*>(x + rowbase + (size_t)c * HWD);
        float4 o;
        o.x = x4.x * (aa4.x + wc);
        o.y = x4.y * (aa4.y + wc);
        o.z = x4.z * (aa4.z + wc);
        o.w = x4.w * (aa4.w + wc);
        *reinterpret_cast<float4*>(out + rowbase + (size_t)c * HWD) = o;
    }
}

extern "C" void kernel_launch(void* const* d_in, const int* in_sizes, int n_in,
                              void* d_out, int out_size, void* d_ws,
                              size_t ws_size, hipStream_t stream) {
    const float* x = (const float*)d_in[0];
    const float* conv_w = (const float*)d_in[1];
    const float* fc_w1 = (const float*)d_in[2];
    const float* fc_w2 = (const float*)d_in[3];
    const float* weight = (const float*)d_in[4];

    float* out = (float*)d_out;
    float* attn_out = out + ATTN_OFF;
    float* w_out = out + W_OFF;
    float* alpha_out = out + ALPHA_OFF;

    // workspace layout (floats)
    float* wsf = (float*)d_ws;
    float* avg_s = wsf;                         // 8*65536
    float* max_s = avg_s + (size_t)BB * HWD;    // 8*65536
    float* partial = max_s + (size_t)BB * HWD;  // 2048*128

    pass1_kernel<<<BB * HH, 256, 0, stream>>>(x, avg_s, max_s, partial);
    mlp_kernel<<<BB, 1024, 0, stream>>>(partial, fc_w1, fc_w2, weight, w_out,
                                        alpha_out);
    conv_mix_kernel<<<BB * HH, 256, 0, stream>>>(x, avg_s, max_s, conv_w,
                                                 w_out, alpha_out, attn_out,
                                                 out);
}

// Round 2
// 541.267 us; speedup vs baseline: 1.0279x; 1.0032x over previous
//
#include <hip/hip_runtime.h>
#include <math.h>

#define BB 8
#define CC 128
#define HH 256
#define WW 256
#define HWD 65536                      // H*W
#define NOUT (67108864)                // B*C*H*W

// d_out packing (floats): out | attn | w | alpha
#define ATTN_OFF ((size_t)NOUT)
#define W_OFF (ATTN_OFF + (size_t)BB * HWD)      // 67633152
#define ALPHA_OFF (W_OFF + (size_t)BB * CC)      // 67634176

__constant__ float g_declo[16] = {
    -0.00011747678400228192f, 0.0006754494059985568f, -0.0003917403729959771f,
    -0.00487035299301066f,    0.008746094047015655f,  0.013981027917015516f,
    -0.04408825393106472f,    -0.01736930100202211f,  0.128747426620186f,
    0.00047248457399797254f,  -0.2840155429624281f,   -0.015829105256023893f,
    0.5853546836548691f,      0.6756307362980128f,    0.3128715909144659f,
    0.05441584224308161f};

__device__ __forceinline__ float sigmoidf_(float v) {
    return 1.0f / (1.0f + expf(-v));
}

// Closed form of a[t] = sum over (j,k), j in [0,135), k in [0,16), with
// sym(2j+k-14)==t of f[k], f[k] = g_declo[15-k] (reversed dec_lo).
__device__ __forceinline__ float a_weight(int t) {
    float v = 0.0f;
    for (int k = (t & 1); k < 16; k += 2) v += g_declo[15 - k];
    if (t <= 13) {
        for (int k = 13 - t; k >= 0; k -= 2) v += g_declo[15 - k];
    }
    if (t >= 242) {
        for (int k = 257 - t; k < 16; k += 2) v += g_declo[15 - k];
    }
    return v;
}

// One block per (b, h-quad). 4 waves; wave r owns row h = 4*hq + r.
// Block-level reads of x are 4 KB contiguous per channel (4 rows x 1 KB).
// Per-pixel sum/max accumulate fully in registers (each thread sees all 128
// channels of its own pixel quad). Row-dots for the wavelet go through the
// conflict-free stride-17 per-wave LDS transpose.
__global__ __launch_bounds__(256) void pass1_kernel(
    const float* __restrict__ x, float* __restrict__ avg_s,
    float* __restrict__ max_s, float* __restrict__ partial) {
    const int blk = blockIdx.x;  // b*64 + hq
    const int b = blk >> 6;
    const int hq = blk & 63;
    const int tid = threadIdx.x;
    const int r = tid >> 6;    // wave = row within quad
    const int lane = tid & 63;
    const int h = (hq << 2) + r;

    __shared__ __align__(16) float a_sh[256];
    __shared__ float T[4][64][17];  // per-wave transpose scratch, stride 17

    a_sh[tid] = a_weight(tid);
    __syncthreads();

    const float4 a4 = reinterpret_cast<const float4*>(a_sh)[lane];
    const float ah = a_sh[h];

    float4 sum4 = {0.f, 0.f, 0.f, 0.f};
    float4 max4 = {-INFINITY, -INFINITY, -INFINITY, -INFINITY};

    const size_t base = (size_t)b * CC * HWD + (size_t)h * WW + (lane << 2);

    for (int cg = 0; cg < 8; ++cg) {
        const int cbase = cg << 4;
        float dots[16];
#pragma unroll
        for (int i = 0; i < 16; ++i) {
            const float4 v = *reinterpret_cast<const float4*>(
                x + base + (size_t)(cbase + i) * HWD);
            dots[i] = a4.x * v.x + a4.y * v.y + a4.z * v.z + a4.w * v.w;
            sum4.x += v.x; sum4.y += v.y; sum4.z += v.z; sum4.w += v.w;
            max4.x = fmaxf(max4.x, v.x); max4.y = fmaxf(max4.y, v.y);
            max4.z = fmaxf(max4.z, v.z); max4.w = fmaxf(max4.w, v.w);
        }
        // wave-private LDS transpose: write 16 dots, read one channel's 16
        // lane-partials. Same-wave DS ordering; no barrier needed.
#pragma unroll
        for (int i = 0; i < 16; ++i) T[r][lane][i] = dots[i];
        const int cr = lane & 15;  // channel within group
        const int q = lane >> 4;   // lane quarter
        float s = 0.f;
#pragma unroll
        for (int j = 0; j < 16; ++j) s += T[r][(q << 4) + j][cr];
        s += __shfl_xor(s, 16, 64);
        s += __shfl_xor(s, 32, 64);
        if (lane < 16)
            partial[((size_t)(b * HH + h)) * CC + cbase + lane] = s * ah;
    }

    const size_t rowoff = (size_t)b * HWD + (size_t)h * WW;
    float4 av = {sum4.x * (1.0f / 128.0f), sum4.y * (1.0f / 128.0f),
                 sum4.z * (1.0f / 128.0f), sum4.w * (1.0f / 128.0f)};
    reinterpret_cast<float4*>(avg_s + rowoff)[lane] = av;
    reinterpret_cast<float4*>(max_s + rowoff)[lane] = max4;
}

// One block per b, 1024 threads: 8 h-groups x 128 channels reduce the
// partials in parallel, then the squeeze-excite MLP. Writes w and alpha.
__global__ __launch_bounds__(1024) void mlp_kernel(
    const float* __restrict__ partial, const float* __restrict__ fc_w1,
    const float* __restrict__ fc_w2, const float* __restrict__ weight,
    float* __restrict__ w_out, float* __restrict__ alpha_out) {
    const int b = blockIdx.x;
    const int t = threadIdx.x;
    const int c = t & 127;
    const int g = t >> 7;  // 0..7

    float acc = 0.0f;
    for (int h = g; h < HH; h += 8)
        acc += partial[((size_t)(b * HH + h)) * CC + c];

    __shared__ float red[8][CC];
    __shared__ float ysh[CC];
    __shared__ float hsh[8];
    red[g][c] = acc;
    __syncthreads();

    if (t < CC) {
        float y = 0.0f;
#pragma unroll
        for (int i = 0; i < 8; ++i) y += red[i][t];
        ysh[t] = y * (1.0f / (135.0f * 135.0f));
    }
    __syncthreads();
    if (t < 8) {
        float ha = 0.0f;
        for (int k = 0; k < CC; ++k) ha += ysh[k] * fc_w1[t * CC + k];
        hsh[t] = fmaxf(ha, 0.0f);
    }
    __syncthreads();
    if (t < CC) {
        float wa = 0.0f;
#pragma unroll
        for (int i = 0; i < 8; ++i) wa += hsh[i] * fc_w2[t * 8 + i];
        w_out[b * CC + t] = sigmoidf_(wa);
    }
    if (b == 0 && t == 0) alpha_out[0] = sigmoidf_(weight[0]);
}

// One block per (b, h-quad). Loads a 10-row zero-padded halo of avg/max into
// LDS, computes 4 attn rows (each thread: its 4 pixels, kept in registers),
// then streams all 128 channels of the 4 rows: out = x*(alpha*attn+(1-a)*w).
// Channel loop runs REVERSED so the x re-read starts on the planes pass1
// touched last (L3 is 256 MB vs x = 268 MB; forward re-read is LRU-worst).
__global__ __launch_bounds__(256) void conv_mix_kernel(
    const float* __restrict__ x, const float* __restrict__ avg_s,
    const float* __restrict__ max_s, const float* __restrict__ cw,
    const float* __restrict__ wvec, const float* __restrict__ alpha_p,
    float* __restrict__ attn_out, float* __restrict__ out) {
    const int blk = blockIdx.x;  // b*64 + hq
    const int b = blk >> 6;
    const int hq = blk & 63;
    const int tid = threadIdx.x;
    const int r = tid >> 6;
    const int lane = tid & 63;
    const int h = (hq << 2) + r;
    const int c0 = lane << 2;  // first of 4 owned columns

    __shared__ float k0[49], k1[49];
    __shared__ float sA[10][262];  // rows 4hq-3 .. 4hq+6, cols -3..258
    __shared__ float sM[10][262];
    __shared__ float wrow[CC];

    // zero everything (halo), then fill interior
    for (int i = tid; i < 2620; i += 256) {
        (&sA[0][0])[i] = 0.f;
        (&sM[0][0])[i] = 0.f;
    }
    if (tid < 49) {
        k0[tid] = cw[tid];
        k1[tid] = cw[49 + tid];
    }
    if (tid < CC) wrow[tid] = wvec[b * CC + tid];
    __syncthreads();
    for (int rr = 0; rr < 10; ++rr) {
        const int row = (hq << 2) - 3 + rr;
        if (row >= 0 && row < HH) {
            sA[rr][3 + tid] = avg_s[(size_t)b * HWD + row * WW + tid];
            sM[rr][3 + tid] = max_s[(size_t)b * HWD + row * WW + tid];
        }
    }
    __syncthreads();

    // 7x7 conv over [avg,max], zero pad; LDS row index = r+kh, col = c+kw.
    float acc0 = 0.f, acc1 = 0.f, acc2 = 0.f, acc3 = 0.f;
#pragma unroll
    for (int kh = 0; kh < 7; ++kh) {
#pragma unroll
        for (int kw = 0; kw < 7; ++kw) {
            const float wa = k0[kh * 7 + kw];
            const float wm = k1[kh * 7 + kw];
            const float* pa = &sA[r + kh][c0 + kw];
            const float* pm = &sM[r + kh][c0 + kw];
            acc0 = fmaf(wa, pa[0], acc0); acc0 = fmaf(wm, pm[0], acc0);
            acc1 = fmaf(wa, pa[1], acc1); acc1 = fmaf(wm, pm[1], acc1);
            acc2 = fmaf(wa, pa[2], acc2); acc2 = fmaf(wm, pm[2], acc2);
            acc3 = fmaf(wa, pa[3], acc3); acc3 = fmaf(wm, pm[3], acc3);
        }
    }
    const float4 att4 = {sigmoidf_(acc0), sigmoidf_(acc1), sigmoidf_(acc2),
                         sigmoidf_(acc3)};
    const size_t rowoff = (size_t)b * HWD + (size_t)h * WW + c0;
    *reinterpret_cast<float4*>(attn_out + rowoff) = att4;

    const float alpha = alpha_p[0];
    const float onem = 1.0f - alpha;
    const float4 aa4 = {alpha * att4.x, alpha * att4.y, alpha * att4.z,
                        alpha * att4.w};
    const size_t base = (size_t)b * CC * HWD + (size_t)h * WW + c0;
#pragma unroll 8
    for (int ci = 127; ci >= 0; --ci) {
        const float wc = onem * wrow[ci];
        const float4 x4 =
            *reinterpret_cast<const float4*>(x + base + (size_t)ci * HWD);
        float4 o;
        o.x = x4.x * (aa4.x + wc);
        o.y = x4.y * (aa4.y + wc);
        o.z = x4.z * (aa4.z + wc);
        o.w = x4.w * (aa4.w + wc);
        *reinterpret_cast<float4*>(out + base + (size_t)ci * HWD) = o;
    }
}

extern "C" void kernel_launch(void* const* d_in, const int* in_sizes, int n_in,
                              void* d_out, int out_size, void* d_ws,
                              size_t ws_size, hipStream_t stream) {
    const float* x = (const float*)d_in[0];
    const float* conv_w = (const float*)d_in[1];
    const float* fc_w1 = (const float*)d_in[2];
    const float* fc_w2 = (const float*)d_in[3];
    const float* weight = (const float*)d_in[4];

    float* out = (float*)d_out;
    float* attn_out = out + ATTN_OFF;
    float* w_out = out + W_OFF;
    float* alpha_out = out + ALPHA_OFF;

    // workspace layout (floats)
    float* wsf = (float*)d_ws;
    float* avg_s = wsf;                         // 8*65536
    float* max_s = avg_s + (size_t)BB * HWD;    // 8*65536
    float* partial = max_s + (size_t)BB * HWD;  // 2048*128

    pass1_kernel<<<BB * 64, 256, 0, stream>>>(x, avg_s, max_s, partial);
    mlp_kernel<<<BB, 1024, 0, stream>>>(partial, fc_w1, fc_w2, weight, w_out,
                                        alpha_out);
    conv_mix_kernel<<<BB * 64, 256, 0, stream>>>(x, avg_s, max_s, conv_w,
                                                 w_out, alpha_out, attn_out,
                                                 out);
}